// Round 13
// baseline (136.906 us; speedup 1.0000x reference)
//
#include <hip/hip_runtime.h>

#define S_SIGMA 8
#define NBINS   16
#define HDIM    1024
#define WDIM    1024
#define GH      129   // (1024-1)/8 + 2
#define GW      129
#define GZ      17    // NBINS + 1
#define CELLS   (GH*GW*GZ)   // 282897 cells per image
#define ROWSZ   (GW*GZ)      // 2193 float2 per grid row (either layout)
#define EPSV    1e-8f
#define FIXS    1048576.0f   // 2^20 fixed-point scale for val accumulation
#define FIXI    (1.0f/1048576.0f)
#define LCELLS  (9*9*16)     // 1296 local bins per 64x64 tile

// ---- splat: pixel-parallel 64x64 tile, fixed-point ds_add_u32 histogram ----
// Coalesced float4 pixel reads; fire-and-forget u32 LDS atomics (r11 lesson);
// flush via no-return global float atomicAdd (low contention: only boundary
// cells are shared, <=4 tiles each). Grid A must be pre-zeroed.
__global__ __launch_bounds__(256) void splat_tile_kernel(
    const float* __restrict__ img, float* __restrict__ grid, int imgBase)
{
    __shared__ unsigned lval[LCELLS];
    __shared__ unsigned lwt [LCELLS];

    int tid = threadIdx.x;
    int tx  = blockIdx.x;   // 0..15
    int ty  = blockIdx.y;   // 0..15
    int b   = blockIdx.z;

    for (int i = tid; i < LCELLS; i += 256) { lval[i] = 0u; lwt[i] = 0u; }
    __syncthreads();

    const float* ib = img + (size_t)(imgBase + b) * (HDIM * WDIM)
                        + (size_t)(ty * 64) * WDIM + tx * 64;

    // 4 iterations x 256 threads x float4 = 4096 px; wave covers 4 full rows
    #pragma unroll
    for (int it = 0; it < 4; ++it) {
        int p   = it * 256 + tid;
        int ly  = p >> 4;            // 16 float4 per 64-px row
        int lx4 = p & 15;
        float4 v4 = *(const float4*)(ib + (size_t)ly * WDIM + lx4 * 4);
        // rintf parity matches global banker's rounding: y*0.125 = 8*ty + ly*0.125,
        // 8*ty even -> tie resolution identical to rintf(ly*0.125).
        int gyl = (int)rintf((float)ly * 0.125f);          // 0..8
        float vv[4] = {v4.x, v4.y, v4.z, v4.w};
        #pragma unroll
        for (int j = 0; j < 4; ++j) {
            float v = vv[j];
            int gxl = (int)rintf((float)(lx4 * 4 + j) * 0.125f);   // 0..8
            int gz  = min(max((int)rintf(v * 15.0f), 0), 15);
            int bin = (gyl * 9 + gxl) * 16 + gz;
            atomicAdd(&lval[bin], (unsigned)rintf(v * FIXS));
            atomicAdd(&lwt [bin], 1u);
        }
    }
    __syncthreads();

    // flush non-empty bins; atomic float add, return value unused
    for (int i = tid; i < LCELLS; i += 256) {
        unsigned w = lwt[i];
        if (w) {
            int gyl = i / 144;
            int rem = i - gyl * 144;
            int gxl = rem >> 4;
            int gz  = rem & 15;
            size_t cell = (((size_t)b * GH + ty * 8 + gyl) * GW + tx * 8 + gxl) * GZ + gz;
            atomicAdd(&grid[2 * cell],     (float)lval[i] * FIXI);
            atomicAdd(&grid[2 * cell + 1], (float)w);
        }
    }
}

// ---- fused y+x+z blur; y-blur intermediate in REGISTERS (no stmp) ----
#define TO 12
#define TI 16
#define NIN  (TI*TI*GZ)    // 4352
#define NTMP (TO*TI*GZ)    // 3264
#define NOUT (TO*TO*GZ)    // 2448
#define NTI  13            // ceil(NTMP/256)
#define NXI  10            // ceil(NOUT/256)

__global__ __launch_bounds__(256) void blur_fused_kernel(
    const float2* __restrict__ in, float2* __restrict__ out,
    const float* __restrict__ kfs, const float* __restrict__ kfr)
{
    __shared__ float2 sbin[NIN];   // input tile; reused for stmp, then xb

    int tid = threadIdx.x;
    int tx0 = blockIdx.x * TO;
    int ty0 = blockIdx.y * TO;
    int b   = blockIdx.z;

    float ks[5] = {kfs[0], kfs[1], kfs[2], kfs[3], kfs[4]};
    float kr[5] = {kfr[0], kfr[1], kfr[2], kfr[3], kfr[4]};

    const float2* gb = in + (size_t)b * CELLS;
    for (int li = tid; li < NIN; li += 256) {
        int iy = li / (TI * GZ);
        int r  = li - iy * (TI * GZ);
        int ix = r / GZ;
        int z  = r - ix * GZ;
        int gy = ty0 - 2 + iy;
        int gx = tx0 - 2 + ix;
        float2 v; v.x = 0.f; v.y = 0.f;
        if (gy >= 0 && gy < GH && gx >= 0 && gx < GW)
            v = gb[((size_t)gy * GW + gx) * GZ + z];
        sbin[li] = v;
    }
    __syncthreads();

    float2 rt[NTI];
    #pragma unroll
    for (int it = 0; it < NTI; ++it) {
        int o = tid + it * 256;
        float2 a; a.x = 0.f; a.y = 0.f;
        if (o < NTMP) {
            int oy = o / (TI * GZ);
            int r  = o - oy * (TI * GZ);
            #pragma unroll
            for (int t = 0; t < 5; ++t) {
                float2 g = sbin[(oy + t) * (TI * GZ) + r];
                a.x += ks[t] * g.x;
                a.y += ks[t] * g.y;
            }
        }
        rt[it] = a;
    }
    __syncthreads();
    #pragma unroll
    for (int it = 0; it < NTI; ++it) {
        int o = tid + it * 256;
        if (o < NTMP) sbin[o] = rt[it];
    }
    __syncthreads();

    float2 rx[NXI];
    #pragma unroll
    for (int it = 0; it < NXI; ++it) {
        int o = tid + it * 256;
        float2 a; a.x = 0.f; a.y = 0.f;
        if (o < NOUT) {
            int oy = o / (TO * GZ);
            int r  = o - oy * (TO * GZ);
            int ox = r / GZ;
            int z  = r - ox * GZ;
            #pragma unroll
            for (int t = 0; t < 5; ++t) {
                float2 g = sbin[(oy * TI + ox + t) * GZ + z];
                a.x += ks[t] * g.x;
                a.y += ks[t] * g.y;
            }
        }
        rx[it] = a;
    }
    __syncthreads();
    #pragma unroll
    for (int it = 0; it < NXI; ++it) {
        int o = tid + it * 256;
        if (o < NOUT) sbin[o] = rx[it];
    }
    __syncthreads();

    // z blur + transposed store: [gy][z][gx]
    float2* ob = out + (size_t)b * CELLS;
    for (int o = tid; o < NOUT; o += 256) {
        int oy = o / (GZ * TO);
        int r2 = o - oy * (GZ * TO);
        int z  = r2 / TO;
        int ox = r2 - z * TO;
        int gy = ty0 + oy;
        int gx = tx0 + ox;
        if (gy < GH && gx < GW) {
            int cb = (oy * TO + ox) * GZ;
            float2 a; a.x = 0.f; a.y = 0.f;
            #pragma unroll
            for (int t = 0; t < 5; ++t) {
                int zz = z + t - 2;
                if (zz >= 0 && zz < GZ) {
                    float2 g = sbin[cb + zz];
                    a.x += kr[t] * g.x;
                    a.y += kr[t] * g.y;
                }
            }
            ob[((size_t)gy * GZ + z) * GW + gx] = a;
        }
    }
}

// ---- slice: grid rows in LDS as [z][r][x0pad] float2 (conflict-free) ----
#define XP2   136
#define RST   XP2
#define ZST   (2*XP2)

__global__ __launch_bounds__(256) void slice_rows_kernel(
    const float* __restrict__ img, const float2* __restrict__ grid,
    float* __restrict__ out, int imgBase)
{
    __shared__ float2 sg[GZ * ZST];   // 36992 B

    int tid = threadIdx.x;
    int k   = blockIdx.x;
    int b   = blockIdx.y;

    const float2* gsrc = grid + (size_t)b * CELLS + (size_t)k * ROWSZ;
    for (int i = tid; i < 2 * ROWSZ; i += 256) {
        int r   = i / ROWSZ;
        int rem = i - r * ROWSZ;
        int z   = rem / GW;
        int x0  = rem - z * GW;
        sg[z * ZST + r * RST + x0] = gsrc[i];
    }
    __syncthreads();

    int x   = tid << 2;
    int x0v = tid >> 1;
    float txb = (float)(x & 7) * 0.125f;

    size_t rowBase = (size_t)(imgBase + b) * (HDIM * WDIM) + (size_t)(k << 3) * WDIM + x;

    #pragma unroll
    for (int r = 0; r < 8; ++r) {
        size_t pixBase = rowBase + (size_t)r * WDIM;
        float4 v4 = *(const float4*)(img + pixBase);
        float ty = (float)r * 0.125f;
        float wy0 = 1.f - ty, wy1 = ty;

        float vv[4] = {v4.x, v4.y, v4.z, v4.w};
        float rr[4];
        #pragma unroll
        for (int j = 0; j < 4; ++j) {
            float v  = vv[j];
            float fz = fminf(fmaxf(v * 15.0f, 0.0f), 15.0f);
            float zf = floorf(fz);
            int   z0 = (int)zf;
            float tz = fz - zf;
            float tx = txb + (float)j * 0.125f;
            float wx0 = 1.f - tx, wx1 = tx;
            float wz0 = 1.f - tz, wz1 = tz;

            int base = z0 * ZST + x0v;
            float2 g000 = sg[base];
            float2 g010 = sg[base + 1];
            float2 g100 = sg[base + RST];
            float2 g110 = sg[base + RST + 1];
            float2 g001 = sg[base + ZST];
            float2 g011 = sg[base + ZST + 1];
            float2 g101 = sg[base + ZST + RST];
            float2 g111 = sg[base + ZST + RST + 1];

            float ov = 0.f, ow = 0.f, w;
            w = wy0 * wx0 * wz0; ov += w * g000.x; ow += w * g000.y;
            w = wy0 * wx0 * wz1; ov += w * g001.x; ow += w * g001.y;
            w = wy0 * wx1 * wz0; ov += w * g010.x; ow += w * g010.y;
            w = wy0 * wx1 * wz1; ov += w * g011.x; ow += w * g011.y;
            w = wy1 * wx0 * wz0; ov += w * g100.x; ow += w * g100.y;
            w = wy1 * wx0 * wz1; ov += w * g101.x; ow += w * g101.y;
            w = wy1 * wx1 * wz0; ov += w * g110.x; ow += w * g110.y;
            w = wy1 * wx1 * wz1; ov += w * g111.x; ow += w * g111.y;
            rr[j] = ov / (ow + EPSV);
        }
        float4 r4; r4.x = rr[0]; r4.y = rr[1]; r4.z = rr[2]; r4.w = rr[3];
        *(float4*)(out + pixBase) = r4;
    }
}

extern "C" void kernel_launch(void* const* d_in, const int* in_sizes, int n_in,
                              void* d_out, int out_size, void* d_ws, size_t ws_size,
                              hipStream_t stream)
{
    const float* img = (const float*)d_in[0];
    const float* fs  = (const float*)d_in[2];
    const float* fr  = (const float*)d_in[3];
    float* out = (float*)d_out;

    int nImgTotal = in_sizes[0] / (HDIM * WDIM);   // 12
    size_t perImgBytes = (size_t)CELLS * 2 * sizeof(float);

    int maxChunk = (int)(ws_size / (2 * perImgBytes));
    if (maxChunk < 1) return;
    if (maxChunk > nImgTotal) maxChunk = nImgTotal;

    const int tilesPerDim = (GH + TO - 1) / TO;    // 11

    for (int base = 0; base < nImgTotal; base += maxChunk) {
        int c = nImgTotal - base;
        if (c > maxChunk) c = maxChunk;

        float* A = (float*)d_ws;
        float* B = A + (size_t)c * CELLS * 2;

        hipMemsetAsync(A, 0, (size_t)c * perImgBytes, stream);

        dim3 sgrid2(16, 16, c);
        splat_tile_kernel<<<sgrid2, 256, 0, stream>>>(img, A, base);

        dim3 bgrid(tilesPerDim, tilesPerDim, c);
        blur_fused_kernel<<<bgrid, 256, 0, stream>>>((const float2*)A, (float2*)B, fs, fr);

        dim3 sgrid(HDIM / 8, c);
        slice_rows_kernel<<<sgrid, 256, 0, stream>>>(img, (const float2*)B, out, base);
    }
}

// Round 14
// 95.240 us; speedup vs baseline: 1.4375x; 1.4375x over previous
//
#include <hip/hip_runtime.h>

#define S_SIGMA 8
#define NBINS   16
#define HDIM    1024
#define WDIM    1024
#define GH      129   // (1024-1)/8 + 2
#define GW      129
#define GZ      17    // NBINS + 1
#define CELLS   (GH*GW*GZ)   // 282897 cells per image
#define ROWSZ   (GW*GZ)      // 2193 float2 per grid row (either layout)
#define EPSV    1e-8f
#define FIXS    1048576.0f   // 2^20 fixed-point scale
#define FIXI    (1.0f/1048576.0f)

// ---- gather splat (r12 version): 4 threads per cell, ds_add_u32 ----
__global__ __launch_bounds__(256) void splat_gather_kernel(
    const float* __restrict__ img, float* __restrict__ grid, int nImg, int imgBase)
{
    __shared__ unsigned lval[16 * 64];   // [gz][cell], bank = cell%32
    __shared__ unsigned lwt [16 * 64];

    int tid = threadIdx.x;
    int c   = tid & 63;
    int q   = tid >> 6;
    int cellIdx = blockIdx.x * 64 + c;
    int total = nImg * GH * GW;

    for (int i = tid; i < 16 * 64; i += 256) { lval[i] = 0u; lwt[i] = 0u; }
    __syncthreads();

    if (cellIdx < total) {
        int b   = cellIdx / (GH * GW);
        int rem = cellIdx - b * (GH * GW);
        int gy  = rem / GW;
        int gx  = rem - gy * GW;
        const float* ib = img + (size_t)(imgBase + b) * (HDIM * WDIM);

        bool interior = (gx >= 1) & (gx <= 127) & (gy >= 1) & (gy <= 127);
        if (interior) {
            int py = gy & 1, px = gx & 1;
            int ylo = 8 * gy - 4 + py;
            int nr  = 9 - 2 * py;
            int ax  = 8 * gx - 4;
            for (int r = q; r < nr; r += 4) {
                const float* rp = ib + (size_t)(ylo + r) * WDIM + ax;
                float4 A = *(const float4*)rp;
                float4 B = *(const float4*)(rp + 4);
                float  cv = rp[8];
                float e7[7] = {A.y, A.z, A.w, B.x, B.y, B.z, B.w};
                #pragma unroll
                for (int j = 0; j < 7; ++j) {
                    float v = e7[j];
                    int gz = min(max((int)rintf(v * 15.0f), 0), 15);
                    atomicAdd(&lval[gz * 64 + c], (unsigned)rintf(v * FIXS));
                    atomicAdd(&lwt [gz * 64 + c], 1u);
                }
                if (!px) {
                    int gz = min(max((int)rintf(A.x * 15.0f), 0), 15);
                    atomicAdd(&lval[gz * 64 + c], (unsigned)rintf(A.x * FIXS));
                    atomicAdd(&lwt [gz * 64 + c], 1u);
                    gz = min(max((int)rintf(cv * 15.0f), 0), 15);
                    atomicAdd(&lval[gz * 64 + c], (unsigned)rintf(cv * FIXS));
                    atomicAdd(&lwt [gz * 64 + c], 1u);
                }
            }
        } else {
            int ylo = max(0, 8 * gy - 4 + (gy & 1));
            int yhi = min(HDIM - 1, 8 * gy + 4 - (gy & 1));
            int xlo = max(0, 8 * gx - 4 + (gx & 1));
            int xhi = min(WDIM - 1, 8 * gx + 4 - (gx & 1));
            for (int y = ylo + q; y <= yhi; y += 4) {
                const float* row = ib + (size_t)y * WDIM;
                for (int x = xlo; x <= xhi; ++x) {
                    float v = row[x];
                    int gz = min(max((int)rintf(v * 15.0f), 0), 15);
                    atomicAdd(&lval[gz * 64 + c], (unsigned)rintf(v * FIXS));
                    atomicAdd(&lwt [gz * 64 + c], 1u);
                }
            }
        }
    }
    __syncthreads();

    if (cellIdx < total) {
        float2* dst = (float2*)grid + (size_t)cellIdx * GZ;
        int zlo = q * 4;
        int zhi = (q == 3) ? 17 : zlo + 4;
        for (int z = zlo; z < zhi; ++z) {
            float2 o;
            if (z == 16) { o.x = 0.f; o.y = 0.f; }
            else {
                o.x = (float)lval[z * 64 + c] * FIXI;
                o.y = (float)lwt [z * 64 + c];
            }
            dst[z] = o;
        }
    }
}

// ---- fused blur, z-half split: TO=8/TI=12, 12.7 KB LDS, VGPR<=64 ----
// h=0: out z 0..8 <- in z 0..10 (nzi=11); h=1: out z 9..16 <- in z 7..16 (nzi=10).
#define TO 8
#define TI 12
#define NZI_MAX 11
#define NTI 5              // ceil(TO*TI*NZI_MAX/256) = ceil(1056/256)
#define NXI 3              // ceil(TO*TO*NZI_MAX/256) = ceil(704/256)

__global__ __launch_bounds__(256, 8) void blur_fused_kernel(
    const float2* __restrict__ in, float2* __restrict__ out,
    const float* __restrict__ kfs, const float* __restrict__ kfr)
{
    __shared__ float2 sbin[TI * TI * NZI_MAX];   // 1584 f2 = 12672 B

    int tid = threadIdx.x;
    int tx0 = blockIdx.x * TO;
    int h   = blockIdx.y & 1;
    int ty0 = (blockIdx.y >> 1) * TO;
    int b   = blockIdx.z;

    int zbase = h * 7;          // first input z
    int nzi   = 11 - h;         // input z planes
    int nzo   = 9 - h;          // output z planes
    int zolo  = 9 * h;          // first output z

    float ks[5] = {kfs[0], kfs[1], kfs[2], kfs[3], kfs[4]};
    float kr[5] = {kfr[0], kfr[1], kfr[2], kfr[3], kfr[4]};

    // load tile (zero pad outside grid)
    const float2* gb = in + (size_t)b * CELLS;
    int nin = TI * TI * nzi;
    for (int li = tid; li < nin; li += 256) {
        int iy = li / (TI * nzi);
        int r  = li - iy * (TI * nzi);
        int ix = r / nzi;
        int zi = r - ix * nzi;
        int gy = ty0 - 2 + iy;
        int gx = tx0 - 2 + ix;
        float2 v; v.x = 0.f; v.y = 0.f;
        if (gy >= 0 && gy < GH && gx >= 0 && gx < GW)
            v = gb[((size_t)gy * GW + gx) * GZ + zbase + zi];
        sbin[li] = v;
    }
    __syncthreads();

    // y blur into registers
    int ntmp = TO * TI * nzi;
    float2 rt[NTI];
    #pragma unroll
    for (int it = 0; it < NTI; ++it) {
        int o = tid + it * 256;
        float2 a; a.x = 0.f; a.y = 0.f;
        if (o < ntmp) {
            int oy = o / (TI * nzi);
            int r  = o - oy * (TI * nzi);
            #pragma unroll
            for (int t = 0; t < 5; ++t) {
                float2 g = sbin[(oy + t) * (TI * nzi) + r];
                a.x += ks[t] * g.x;
                a.y += ks[t] * g.y;
            }
        }
        rt[it] = a;
    }
    __syncthreads();
    #pragma unroll
    for (int it = 0; it < NTI; ++it) {
        int o = tid + it * 256;
        if (o < ntmp) sbin[o] = rt[it];   // [oy][ix][zi]
    }
    __syncthreads();

    // x blur into registers
    int nx = TO * TO * nzi;
    float2 rx[NXI];
    #pragma unroll
    for (int it = 0; it < NXI; ++it) {
        int o = tid + it * 256;
        float2 a; a.x = 0.f; a.y = 0.f;
        if (o < nx) {
            int oy = o / (TO * nzi);
            int r  = o - oy * (TO * nzi);
            int ox = r / nzi;
            int zi = r - ox * nzi;
            #pragma unroll
            for (int t = 0; t < 5; ++t) {
                float2 g = sbin[oy * (TI * nzi) + (ox + t) * nzi + zi];
                a.x += ks[t] * g.x;
                a.y += ks[t] * g.y;
            }
        }
        rx[it] = a;
    }
    __syncthreads();
    #pragma unroll
    for (int it = 0; it < NXI; ++it) {
        int o = tid + it * 256;
        if (o < nx) sbin[o] = rx[it];     // xb: [oy][ox][zi]
    }
    __syncthreads();

    // z blur + transposed store [gy][z][gx]; order (oy, zo, ox) for coalescing
    float2* ob = out + (size_t)b * CELLS;
    int nout = TO * TO * nzo;
    for (int o = tid; o < nout; o += 256) {
        int oy = o / (nzo * TO);
        int r2 = o - oy * (nzo * TO);
        int k  = r2 / TO;
        int ox = r2 - k * TO;
        int zo = zolo + k;
        int gy = ty0 + oy;
        int gx = tx0 + ox;
        if (gy < GH && gx < GW) {
            int cb = (oy * TO + ox) * nzi;
            float2 a; a.x = 0.f; a.y = 0.f;
            #pragma unroll
            for (int t = 0; t < 5; ++t) {
                int zg = zo + t - 2;
                if (zg >= 0 && zg <= 16) {
                    float2 g = sbin[cb + zg - zbase];
                    a.x += kr[t] * g.x;
                    a.y += kr[t] * g.y;
                }
            }
            ob[((size_t)gy * GZ + zo) * GW + gx] = a;
        }
    }
}

// ---- slice: grid rows in LDS as [z][r][x0pad] float2 (conflict-free) ----
#define XP2   136
#define RST   XP2
#define ZST   (2*XP2)

__global__ __launch_bounds__(256) void slice_rows_kernel(
    const float* __restrict__ img, const float2* __restrict__ grid,
    float* __restrict__ out, int imgBase)
{
    __shared__ float2 sg[GZ * ZST];   // 36992 B

    int tid = threadIdx.x;
    int k   = blockIdx.x;
    int b   = blockIdx.y;

    const float2* gsrc = grid + (size_t)b * CELLS + (size_t)k * ROWSZ;
    for (int i = tid; i < 2 * ROWSZ; i += 256) {
        int r   = i / ROWSZ;
        int rem = i - r * ROWSZ;
        int z   = rem / GW;
        int x0  = rem - z * GW;
        sg[z * ZST + r * RST + x0] = gsrc[i];
    }
    __syncthreads();

    int x   = tid << 2;
    int x0v = tid >> 1;
    float txb = (float)(x & 7) * 0.125f;

    size_t rowBase = (size_t)(imgBase + b) * (HDIM * WDIM) + (size_t)(k << 3) * WDIM + x;

    #pragma unroll
    for (int r = 0; r < 8; ++r) {
        size_t pixBase = rowBase + (size_t)r * WDIM;
        float4 v4 = *(const float4*)(img + pixBase);
        float ty = (float)r * 0.125f;
        float wy0 = 1.f - ty, wy1 = ty;

        float vv[4] = {v4.x, v4.y, v4.z, v4.w};
        float rr[4];
        #pragma unroll
        for (int j = 0; j < 4; ++j) {
            float v  = vv[j];
            float fz = fminf(fmaxf(v * 15.0f, 0.0f), 15.0f);
            float zf = floorf(fz);
            int   z0 = (int)zf;
            float tz = fz - zf;
            float tx = txb + (float)j * 0.125f;
            float wx0 = 1.f - tx, wx1 = tx;
            float wz0 = 1.f - tz, wz1 = tz;

            int base = z0 * ZST + x0v;
            float2 g000 = sg[base];
            float2 g010 = sg[base + 1];
            float2 g100 = sg[base + RST];
            float2 g110 = sg[base + RST + 1];
            float2 g001 = sg[base + ZST];
            float2 g011 = sg[base + ZST + 1];
            float2 g101 = sg[base + ZST + RST];
            float2 g111 = sg[base + ZST + RST + 1];

            float ov = 0.f, ow = 0.f, w;
            w = wy0 * wx0 * wz0; ov += w * g000.x; ow += w * g000.y;
            w = wy0 * wx0 * wz1; ov += w * g001.x; ow += w * g001.y;
            w = wy0 * wx1 * wz0; ov += w * g010.x; ow += w * g010.y;
            w = wy0 * wx1 * wz1; ov += w * g011.x; ow += w * g011.y;
            w = wy1 * wx0 * wz0; ov += w * g100.x; ow += w * g100.y;
            w = wy1 * wx0 * wz1; ov += w * g101.x; ow += w * g101.y;
            w = wy1 * wx1 * wz0; ov += w * g110.x; ow += w * g110.y;
            w = wy1 * wx1 * wz1; ov += w * g111.x; ow += w * g111.y;
            rr[j] = ov / (ow + EPSV);
        }
        float4 r4; r4.x = rr[0]; r4.y = rr[1]; r4.z = rr[2]; r4.w = rr[3];
        *(float4*)(out + pixBase) = r4;
    }
}

extern "C" void kernel_launch(void* const* d_in, const int* in_sizes, int n_in,
                              void* d_out, int out_size, void* d_ws, size_t ws_size,
                              hipStream_t stream)
{
    const float* img = (const float*)d_in[0];
    const float* fs  = (const float*)d_in[2];
    const float* fr  = (const float*)d_in[3];
    float* out = (float*)d_out;

    int nImgTotal = in_sizes[0] / (HDIM * WDIM);   // 12
    size_t perImgBytes = (size_t)CELLS * 2 * sizeof(float);

    int maxChunk = (int)(ws_size / (2 * perImgBytes));
    if (maxChunk < 1) return;
    if (maxChunk > nImgTotal) maxChunk = nImgTotal;

    const int tilesPerDim = (GH + TO - 1) / TO;    // 17 for TO=8

    for (int base = 0; base < nImgTotal; base += maxChunk) {
        int c = nImgTotal - base;
        if (c > maxChunk) c = maxChunk;

        float* A = (float*)d_ws;
        float* B = A + (size_t)c * CELLS * 2;

        int nCells = c * GH * GW;
        int cellBlocks = (nCells + 63) / 64;
        splat_gather_kernel<<<cellBlocks, 256, 0, stream>>>(img, A, c, base);

        dim3 bgrid(tilesPerDim, tilesPerDim * 2, c);   // y-dim encodes (tile_y, z-half)
        blur_fused_kernel<<<bgrid, 256, 0, stream>>>((const float2*)A, (float2*)B, fs, fr);

        dim3 sgrid(HDIM / 8, c);
        slice_rows_kernel<<<sgrid, 256, 0, stream>>>(img, (const float2*)B, out, base);
    }
}